// Round 17
// baseline (460.789 us; speedup 1.0000x reference)
//
#include <hip/hip_runtime.h>

#define N_NEWS 50000
#define N_USERS 100000
#define N_ATR 1000
#define E_ATR 100000
#define E_USR 2000000
#define EPSF 1e-8f

#define ACAP 192   // attr bucket capacity
#define NCAP 24    // news bucket capacity
#define P_USR 250  // user partitions (coarse sort)
#define UPP 400    // users per partition
#define ACAPP 9216 // arena capacity per partition
#define EBLK_A 4096

typedef short s16x8 __attribute__((ext_vector_type(8)));
typedef float f32x4 __attribute__((ext_vector_type(4)));

__device__ inline ushort f2bf(float f) {
    uint u = __float_as_uint(f);
    u += 0x7fffu + ((u >> 16) & 1u);
    return (ushort)(u >> 16);
}
__device__ inline float bflo(uint v) { return __uint_as_float(v << 16); }
__device__ inline float bfhi(uint v) { return __uint_as_float(v & 0xffff0000u); }
__device__ inline float fast_tanh(float x) {
    x = fminf(fmaxf(x, -15.0f), 15.0f);
    float e = __expf(2.0f * x);
    return (e - 1.0f) / (e + 1.0f);
}
__device__ inline s16x8 cvt8(const float* p) {
    float4 x0 = *(const float4*)p;
    float4 x1 = *(const float4*)(p + 4);
    s16x8 v;
    v[0] = (short)f2bf(x0.x); v[1] = (short)f2bf(x0.y);
    v[2] = (short)f2bf(x0.z); v[3] = (short)f2bf(x0.w);
    v[4] = (short)f2bf(x1.x); v[5] = (short)f2bf(x1.y);
    v[6] = (short)f2bf(x1.z); v[7] = (short)f2bf(x1.w);
    return v;
}

struct TrJob { const float* src; ushort* dst; int R, C, blkEnd; };

// ========== prep: usr counting-sort + atr/news fill + weight transposes ======
// (cvt role DELETED — R15/R16 lesson: the f32->bf16 streaming copy caps at
// ~2.3 TB/s regardless of structure; consumers now read f32 directly.)
struct PrepArgs {
    const int *atr_row, *atr_col, *usr_row, *usr_col;
    int *cnt_atr, *cnt_news, *arena_cnt;
    int *ids_atr, *ids_news;
    unsigned long long* arena;
    int pa, fa, tr;
    TrJob j[6];
};

__global__ void prep_k(PrepArgs A) {
    __shared__ float tile[32][33];
    __shared__ int cloc[256], cscn[256], sexc[256], cbase[256];
    __shared__ ushort stageI[EBLK_A];
    int b = blockIdx.x;
    int t = threadIdx.x;
    if (b < A.pa) {
        cloc[t] = 0;
        __syncthreads();
        int base = b * EBLK_A;
        int endE = base + EBLK_A; if (endE > E_USR) endE = E_USR;
        int n = endE - base;
        for (int e = base + t; e < endE; e += 256)
            atomicAdd(&cloc[A.usr_col[e] / UPP], 1);
        __syncthreads();
        cscn[t] = cloc[t];
        __syncthreads();
        for (int off = 1; off < 256; off <<= 1) {
            int v = (t >= off) ? cscn[t - off] : 0;
            __syncthreads();
            cscn[t] += v;
            __syncthreads();
        }
        sexc[t] = cscn[t] - cloc[t];
        if (t < P_USR) cbase[t] = atomicAdd(&A.arena_cnt[t], cloc[t]);
        cloc[t] = 0;
        __syncthreads();
        for (int e = base + t; e < endE; e += 256) {
            int p = A.usr_col[e] / UPP;
            int off = atomicAdd(&cloc[p], 1);
            stageI[sexc[p] + off] = (ushort)(e - base);
        }
        __syncthreads();
        for (int i = t; i < n; i += 256) {
            int e = base + stageI[i];
            int c = A.usr_col[e];
            int r = A.usr_row[e];
            int p = c / UPP;
            int dst = cbase[p] + (i - sexc[p]);
            if (dst < ACAPP)
                A.arena[(size_t)p * ACAPP + dst] =
                    ((unsigned long long)(uint)c << 32) | (uint)r;
        }
        return;
    }
    b -= A.pa;
    if (b < A.fa) {
        int total = 2 * E_ATR;
        int per = (total + A.fa - 1) / A.fa;
        int base = b * per;
        int endE = base + per; if (endE > total) endE = total;
        for (int e = base + t; e < endE; e += 256) {
            if (e < E_ATR) {
                int c = A.atr_col[e];
                int slot = atomicAdd(&A.cnt_atr[c], 1);
                if (slot < ACAP) A.ids_atr[(size_t)c * ACAP + slot] = A.atr_row[e];
            } else {
                int e2 = e - E_ATR;
                int r = A.atr_row[e2];
                int slot = atomicAdd(&A.cnt_news[r], 1);
                if (slot < NCAP) A.ids_news[(size_t)r * NCAP + slot] = A.atr_col[e2];
            }
        }
        return;
    }
    b -= A.fa;
    // ---- weight transpose+cvt ----
    int ji = 0;
    while (b >= A.j[ji].blkEnd) ++ji;
    const TrJob& J = A.j[ji];
    int lb = b - (ji ? A.j[ji - 1].blkEnd : 0);
    int ctiles = J.C / 32;
    int bc = (lb % ctiles) * 32, br = (lb / ctiles) * 32;
    int tx = t & 31, ty = t >> 5;
    for (int i = 0; i < 4; ++i)
        tile[ty + i * 8][tx] = J.src[(size_t)(br + ty + i * 8) * J.C + bc + tx];
    __syncthreads();
    for (int i = 0; i < 4; ++i)
        J.dst[(size_t)(bc + ty + i * 8) * J.R + br + tx] = f2bf(tile[tx][ty + i * 8]);
}

// ===== mid kernel: usr pass B (CSR) + gather768 (f32 src -> bf16 agr) =====
struct MidArgs {
    const unsigned long long* arena;
    const int* arena_cnt;
    int *cnt_usr, *start_usr, *ids_usr;
    const float* news_x;
    const int* ids_atr;
    const int* cnt_atr;
    ushort* agr_atr_b;
};

__global__ void mid_k(MidArgs M) {
    __shared__ int cnt[512];
    __shared__ int scn[512];
    int b = blockIdx.x;
    int t = threadIdx.x;
    if (b < P_USR) {
        int p = b;
        int nA = M.arena_cnt[p]; if (nA > ACAPP) nA = ACAPP;
        const unsigned long long* ar = M.arena + (size_t)p * ACAPP;
        cnt[t] = 0; cnt[t + 256] = 0;
        __syncthreads();
        for (int i = t; i < nA; i += 256)
            atomicAdd(&cnt[(int)(ar[i] >> 32) - p * UPP], 1);
        __syncthreads();
        scn[t] = cnt[t]; scn[t + 256] = cnt[t + 256];
        __syncthreads();
        for (int off = 1; off < 512; off <<= 1) {
            int v0 = (t >= off) ? scn[t - off] : 0;
            int v1 = ((t + 256) >= off) ? scn[t + 256 - off] : 0;
            __syncthreads();
            scn[t] += v0; scn[t + 256] += v1;
            __syncthreads();
        }
        for (int i = t; i < UPP; i += 256) {
            int u = p * UPP + i;
            M.cnt_usr[u] = cnt[i];
            M.start_usr[u] = p * ACAPP + (scn[i] - cnt[i]);
        }
        __syncthreads();
        for (int i = t; i < UPP; i += 256) cnt[i] = scn[i] - cnt[i];
        __syncthreads();
        for (int i = t; i < nA; i += 256) {
            unsigned long long v = ar[i];
            int c = (int)(v >> 32);
            int off = atomicAdd(&cnt[c - p * UPP], 1);
            M.ids_usr[(size_t)p * ACAPP + off] = (int)(v & 0xffffffffu);
        }
        return;
    }
    b -= P_USR;
    // ---- gather 768-dim news(f32) -> attr bf16, 4-way ILP ----
    int u = b;
    int dc = M.cnt_atr[u];
    int d = dc < ACAP ? dc : ACAP;
    const int* bp = M.ids_atr + (size_t)u * ACAP;
    float a0 = 0.f, a1 = 0.f, a2 = 0.f, a3 = 0.f;
    int i = 0;
    for (; i + 3 < d; i += 4) {
        const float2* r0 = (const float2*)(M.news_x + (size_t)bp[i] * 768);
        const float2* r1 = (const float2*)(M.news_x + (size_t)bp[i + 1] * 768);
        const float2* r2 = (const float2*)(M.news_x + (size_t)bp[i + 2] * 768);
        const float2* r3 = (const float2*)(M.news_x + (size_t)bp[i + 3] * 768);
        float2 v0 = r0[t], v1 = r1[t], v2 = r2[t], v3 = r3[t];
        a0 += v0.x + v1.x + v2.x + v3.x;
        a1 += v0.y + v1.y + v2.y + v3.y;
        if (t < 128) {
            float2 w0 = r0[256 + t], w1 = r1[256 + t], w2 = r2[256 + t], w3 = r3[256 + t];
            a2 += w0.x + w1.x + w2.x + w3.x;
            a3 += w0.y + w1.y + w2.y + w3.y;
        }
    }
    for (; i < d; ++i) {
        const float2* r0 = (const float2*)(M.news_x + (size_t)bp[i] * 768);
        float2 v0 = r0[t];
        a0 += v0.x; a1 += v0.y;
        if (t < 128) {
            float2 w0 = r0[256 + t];
            a2 += w0.x; a3 += w0.y;
        }
    }
    float inv = 1.0f / ((float)dc + EPSF);
    uint* dst = (uint*)(M.agr_atr_b + (size_t)u * 768);
    dst[t] = (uint)f2bf(a0 * inv) | ((uint)f2bf(a1 * inv) << 16);
    if (t < 128)
        dst[256 + t] = (uint)f2bf(a2 * inv) | ((uint)f2bf(a3 * inv) << 16);
}

// ------- gather 128-dim (bucket layout), 32 lanes/dest -------
template<int CAP>
__global__ void gather128c_k(const ushort* __restrict__ srcp, const int* __restrict__ ids,
                             const int* __restrict__ cnt, ushort* __restrict__ agr, int n) {
    int u = blockIdx.x * 8 + (threadIdx.x >> 5);
    if (u >= n) return;
    int lane = threadIdx.x & 31;
    int dc = cnt[u];
    int d = dc < CAP ? dc : CAP;
    const int* bp = ids + (size_t)u * CAP;
    float a0 = 0.f, a1 = 0.f, a2 = 0.f, a3 = 0.f;
    int i = 0;
    for (; i + 3 < d; i += 4) {
        int s0 = bp[i], s1 = bp[i + 1], s2 = bp[i + 2], s3 = bp[i + 3];
        uint2 v0 = *((const uint2*)(srcp + (size_t)s0 * 128) + lane);
        uint2 v1 = *((const uint2*)(srcp + (size_t)s1 * 128) + lane);
        uint2 v2 = *((const uint2*)(srcp + (size_t)s2 * 128) + lane);
        uint2 v3 = *((const uint2*)(srcp + (size_t)s3 * 128) + lane);
        a0 += bflo(v0.x) + bflo(v1.x) + bflo(v2.x) + bflo(v3.x);
        a1 += bfhi(v0.x) + bfhi(v1.x) + bfhi(v2.x) + bfhi(v3.x);
        a2 += bflo(v0.y) + bflo(v1.y) + bflo(v2.y) + bflo(v3.y);
        a3 += bfhi(v0.y) + bfhi(v1.y) + bfhi(v2.y) + bfhi(v3.y);
    }
    for (; i < d; ++i) {
        uint2 v0 = *((const uint2*)(srcp + (size_t)bp[i] * 128) + lane);
        a0 += bflo(v0.x); a1 += bfhi(v0.x);
        a2 += bflo(v0.y); a3 += bfhi(v0.y);
    }
    float inv = 1.0f / ((float)dc + EPSF);
    uint2 packed;
    packed.x = (uint)f2bf(a0 * inv) | ((uint)f2bf(a1 * inv) << 16);
    packed.y = (uint)f2bf(a2 * inv) | ((uint)f2bf(a3 * inv) << 16);
    *((uint2*)(agr + (size_t)u * 128) + lane) = packed;
}

// ------- gather 128-dim (CSR layout), 32 lanes/dest -------
__global__ void gather128s_k(const ushort* __restrict__ srcp, const int* __restrict__ ids,
                             const int* __restrict__ start, const int* __restrict__ cnt,
                             ushort* __restrict__ agr, int n) {
    int u = blockIdx.x * 8 + (threadIdx.x >> 5);
    if (u >= n) return;
    int lane = threadIdx.x & 31;
    int d = cnt[u];
    const int* bp = ids + start[u];
    float a0 = 0.f, a1 = 0.f, a2 = 0.f, a3 = 0.f;
    int i = 0;
    for (; i + 3 < d; i += 4) {
        int s0 = bp[i], s1 = bp[i + 1], s2 = bp[i + 2], s3 = bp[i + 3];
        uint2 v0 = *((const uint2*)(srcp + (size_t)s0 * 128) + lane);
        uint2 v1 = *((const uint2*)(srcp + (size_t)s1 * 128) + lane);
        uint2 v2 = *((const uint2*)(srcp + (size_t)s2 * 128) + lane);
        uint2 v3 = *((const uint2*)(srcp + (size_t)s3 * 128) + lane);
        a0 += bflo(v0.x) + bflo(v1.x) + bflo(v2.x) + bflo(v3.x);
        a1 += bfhi(v0.x) + bfhi(v1.x) + bfhi(v2.x) + bfhi(v3.x);
        a2 += bflo(v0.y) + bflo(v1.y) + bflo(v2.y) + bflo(v3.y);
        a3 += bfhi(v0.y) + bfhi(v1.y) + bfhi(v2.y) + bfhi(v3.y);
    }
    for (; i < d; ++i) {
        uint2 v0 = *((const uint2*)(srcp + (size_t)bp[i] * 128) + lane);
        a0 += bflo(v0.x); a1 += bfhi(v0.x);
        a2 += bflo(v0.y); a3 += bfhi(v0.y);
    }
    float inv = 1.0f / ((float)d + EPSF);
    uint2 packed;
    packed.x = (uint)f2bf(a0 * inv) | ((uint)f2bf(a1 * inv) << 16);
    packed.y = (uint)f2bf(a2 * inv) | ((uint)f2bf(a3 * inv) << 16);
    *((uint2*)(agr + (size_t)u * 128) + lane) = packed;
}

// ================= m97-style MFMA GEMM (XCD-swizzled 1-D grid) =================
// A1F32: A1 is f32 [M][NS1*64]; reg-staged (load 32B f32, cvt, swizzled
// ds_write_b128). Other chunks + B use global_load_lds with pre-swizzled src.
template<int NS, int NS1, bool TANH, int OMODE, int GY, bool A1F32>
__launch_bounds__(256, 3)
__global__ void gemm5_k(const ushort* __restrict__ A1, const ushort* __restrict__ A2,
                        const ushort* __restrict__ Bt, const float* __restrict__ bias,
                        float* __restrict__ outf, ushort* __restrict__ outb,
                        int M, int N) {
    __shared__ __align__(16) char lds[32768];
    const int t = threadIdx.x;
    const int w = t >> 6, l = t & 63, lr = l & 15, lk = l >> 4;
    const int wm = w >> 1, wn = w & 1;
    int nwg = gridDim.x;
    int q = nwg >> 3, r = nwg & 7;
    int xcd = blockIdx.x & 7, idx = blockIdx.x >> 3;
    int fid = (xcd < r) ? xcd * (q + 1) + idx : r * (q + 1) + (xcd - r) * q + idx;
    constexpr int LG = (GY == 4) ? 2 : (GY == 2) ? 1 : 0;
    const int row0 = (fid >> LG) * 128;
    const int col0 = (fid & (GY - 1)) * 128;
    constexpr int A1RB = NS1 * 128;     // bf16 row bytes
    constexpr int A2RB = (NS - NS1) * 128;
    constexpr int BRB = NS * 128;

    auto stage = [&](int s) {
        if (A1F32 && s < NS1) {
            const float* Af = (const float*)A1;
#pragma unroll
            for (int i = 0; i < 4; ++i) {
                int chunk = i * 256 + t;
                int row = chunk >> 3, sub = chunk & 7;
                int rg = row0 + row; if (rg >= M) rg = M - 1;
                s16x8 v = cvt8(Af + (size_t)rg * (NS1 * 64) + s * 64 + sub * 8);
                *(s16x8*)(lds + row * 128 + ((sub * 16) ^ ((row & 7) << 4))) = v;
            }
        } else {
            const char* abase; int arb, soff;
            if (s < NS1) { abase = (const char*)A1; arb = A1RB; soff = s * 128; }
            else         { abase = (const char*)A2; arb = A2RB; soff = (s - NS1) * 128; }
#pragma unroll
            for (int i = 0; i < 4; ++i) {
                int chunk = i * 256 + w * 64 + l;
                int row = chunk >> 3, sub = chunk & 7;
                int rg = row0 + row; if (rg >= M) rg = M - 1;
                const char* src = abase + (size_t)rg * arb + soff + ((sub * 16) ^ ((row & 7) << 4));
                __builtin_amdgcn_global_load_lds(
                    (const __attribute__((address_space(1))) unsigned int*)src,
                    (__attribute__((address_space(3))) unsigned int*)(lds + i * 4096 + w * 1024),
                    16, 0, 0);
            }
        }
#pragma unroll
        for (int i = 0; i < 4; ++i) {
            int chunk = i * 256 + w * 64 + l;
            int row = chunk >> 3, sub = chunk & 7;
            const char* src = (const char*)Bt + (size_t)(col0 + row) * BRB + s * 128
                              + ((sub * 16) ^ ((row & 7) << 4));
            __builtin_amdgcn_global_load_lds(
                (const __attribute__((address_space(1))) unsigned int*)src,
                (__attribute__((address_space(3))) unsigned int*)(lds + 16384 + i * 4096 + w * 1024),
                16, 0, 0);
        }
    };

    f32x4 acc[4][4];
#pragma unroll
    for (int i = 0; i < 4; ++i)
#pragma unroll
        for (int j = 0; j < 4; ++j) acc[i][j] = (f32x4)0.f;

    stage(0);
    for (int s = 0; s < NS; ++s) {
        __syncthreads();
#pragma unroll
        for (int ks = 0; ks < 2; ++ks) {
            s16x8 af[4], bf[4];
#pragma unroll
            for (int rt = 0; rt < 4; ++rt) {
                int rr = wm * 64 + rt * 16 + lr;
                af[rt] = *(const s16x8*)(lds + rr * 128 + ((ks * 64 + lk * 16) ^ ((rr & 7) << 4)));
            }
#pragma unroll
            for (int ct = 0; ct < 4; ++ct) {
                int c = wn * 64 + ct * 16 + lr;
                bf[ct] = *(const s16x8*)(lds + 16384 + c * 128 + ((ks * 64 + lk * 16) ^ ((c & 7) << 4)));
            }
#pragma unroll
            for (int rt = 0; rt < 4; ++rt)
#pragma unroll
                for (int ct = 0; ct < 4; ++ct)
                    acc[rt][ct] = __builtin_amdgcn_mfma_f32_16x16x32_bf16(
                        af[rt], bf[ct], acc[rt][ct], 0, 0, 0);
        }
        __syncthreads();
        if (s + 1 < NS) stage(s + 1);
    }

    if (OMODE == 0) {
#pragma unroll
        for (int rt = 0; rt < 4; ++rt)
#pragma unroll
            for (int ct = 0; ct < 4; ++ct) {
                int c = wn * 64 + ct * 16 + lr;
                float bs = bias[col0 + c];
#pragma unroll
                for (int r4 = 0; r4 < 4; ++r4) {
                    int rr = wm * 64 + rt * 16 + lk * 4 + r4;
                    float v = acc[rt][ct][r4] + bs;
                    if (TANH) v = fast_tanh(v);
                    *(ushort*)(lds + rr * 256 + ((c * 2) ^ ((rr & 7) << 4))) = f2bf(v);
                }
            }
        __syncthreads();
#pragma unroll
        for (int i = 0; i < 8; ++i) {
            int chunk = i * 256 + t;
            int rr = chunk >> 4, cb = (chunk & 15) * 16;
            int rg = row0 + rr;
            if (rg < M)
                *(float4*)((char*)outb + (size_t)rg * (N * 2) + col0 * 2 + cb) =
                    *(const float4*)(lds + rr * 256 + (cb ^ ((rr & 7) << 4)));
        }
    } else {
#pragma unroll
        for (int rt = 0; rt < 4; ++rt)
#pragma unroll
            for (int ct = 0; ct < 4; ++ct) {
                int c = col0 + wn * 64 + ct * 16 + lr;
                float bs = bias[c];
#pragma unroll
                for (int r4 = 0; r4 < 4; ++r4) {
                    int rg = row0 + wm * 64 + rt * 16 + lk * 4 + r4;
                    if (rg < M) {
                        float v = acc[rt][ct][r4] + bs;
                        if (TANH) v = fast_tanh(v);
                        outf[(size_t)rg * N + c] = v;
                        if (OMODE == 2) outb[(size_t)rg * N + c] = f2bf(v);
                    }
                }
            }
    }
}

// ========== fused users MLP: concat(f32 128, bf16 128) -> 256 tanh -> 128 ====
__launch_bounds__(256, 3)
__global__ void mlp_users_fused(const float* __restrict__ users_x,
                                const ushort* __restrict__ agr_b,
                                const ushort* __restrict__ wuat,  // [256][256]
                                const float* __restrict__ bua,
                                const ushort* __restrict__ wubt,  // [128][256]
                                const float* __restrict__ bub,
                                float* __restrict__ outf, int M) {
    __shared__ __align__(16) char lds[32768];   // A/h [64][512B] swizzled
    const int t = threadIdx.x;
    const int w = t >> 6, l = t & 63, lr = l & 15, lk = l >> 4;
    const int row0 = blockIdx.x * 64;

    // reg-stage A: f32 half cvt'd, bf16 half copied; swizzled ds_write_b128
#pragma unroll
    for (int i = 0; i < 8; ++i) {
        int chunk = i * 256 + t;
        int row = chunk >> 5, sc = chunk & 31;
        int rg = row0 + row; if (rg >= M) rg = M - 1;
        s16x8 v;
        if (sc < 16) v = cvt8(users_x + (size_t)rg * 128 + sc * 8);
        else         v = *(const s16x8*)(agr_b + (size_t)rg * 128 + (sc - 16) * 8);
        *(s16x8*)(lds + ((row * 512 + sc * 16) ^ ((row & 7) << 4))) = v;
    }
    __syncthreads();

    // ---- GEMM1: (64x256)@(256x256); wave w owns hidden cols [w*64, +64) ----
    f32x4 acc[4][4];
#pragma unroll
    for (int i = 0; i < 4; ++i)
#pragma unroll
        for (int j = 0; j < 4; ++j) acc[i][j] = (f32x4)0.f;
#pragma unroll
    for (int ks = 0; ks < 8; ++ks) {
        s16x8 af[4], bf[4];
#pragma unroll
        for (int rt = 0; rt < 4; ++rt) {
            int rr = rt * 16 + lr;
            af[rt] = *(const s16x8*)(lds + ((rr * 512 + ks * 64 + lk * 16) ^ ((rr & 7) << 4)));
        }
#pragma unroll
        for (int ct = 0; ct < 4; ++ct) {
            int c = w * 64 + ct * 16 + lr;
            bf[ct] = *(const s16x8*)(wuat + (size_t)c * 256 + ks * 32 + lk * 8);
        }
#pragma unroll
        for (int rt = 0; rt < 4; ++rt)
#pragma unroll
            for (int ct = 0; ct < 4; ++ct)
                acc[rt][ct] = __builtin_amdgcn_mfma_f32_16x16x32_bf16(
                    af[rt], bf[ct], acc[rt][ct], 0, 0, 0);
    }
    __syncthreads();

    // tanh + bias -> h LDS
#pragma unroll
    for (int rt = 0; rt < 4; ++rt)
#pragma unroll
        for (int ct = 0; ct < 4; ++ct) {
            int c = w * 64 + ct * 16 + lr;
            float bs = bua[c];
#pragma unroll
            for (int r4 = 0; r4 < 4; ++r4) {
                int rr = rt * 16 + lk * 4 + r4;
                ushort h = f2bf(fast_tanh(acc[rt][ct][r4] + bs));
                *(ushort*)(lds + ((rr * 512 + c * 2) ^ ((rr & 7) << 4))) = h;
            }
        }
    __syncthreads();

    // ---- GEMM2: (64x256)@(256x128); wave w owns out cols [w*32, +32) ----
    f32x4 acc2[4][2];
#pragma unroll
    for (int i = 0; i < 4; ++i)
#pragma unroll
        for (int j = 0; j < 2; ++j) acc2[i][j] = (f32x4)0.f;
#pragma unroll
    for (int ks = 0; ks < 8; ++ks) {
        s16x8 af[4], bf[2];
#pragma unroll
        for (int rt = 0; rt < 4; ++rt) {
            int rr = rt * 16 + lr;
            af[rt] = *(const s16x8*)(lds + ((rr * 512 + ks * 64 + lk * 16) ^ ((rr & 7) << 4)));
        }
#pragma unroll
        for (int ct = 0; ct < 2; ++ct) {
            int c = w * 32 + ct * 16 + lr;
            bf[ct] = *(const s16x8*)(wubt + (size_t)c * 256 + ks * 32 + lk * 8);
        }
#pragma unroll
        for (int rt = 0; rt < 4; ++rt)
#pragma unroll
            for (int ct = 0; ct < 2; ++ct)
                acc2[rt][ct] = __builtin_amdgcn_mfma_f32_16x16x32_bf16(
                    af[rt], bf[ct], acc2[rt][ct], 0, 0, 0);
    }
#pragma unroll
    for (int rt = 0; rt < 4; ++rt)
#pragma unroll
        for (int ct = 0; ct < 2; ++ct) {
            int c = w * 32 + ct * 16 + lr;
            float bs = bub[c];
#pragma unroll
            for (int r4 = 0; r4 < 4; ++r4) {
                int rg = row0 + rt * 16 + lk * 4 + r4;
                if (rg < M) outf[(size_t)rg * 128 + c] = acc2[rt][ct][r4] + bs;
            }
        }
}

extern "C" void kernel_launch(void* const* d_in, const int* in_sizes, int n_in,
                              void* d_out, int out_size, void* d_ws, size_t ws_size,
                              hipStream_t stream) {
    const float* news_x  = (const float*)d_in[0];
    const float* users_x = (const float*)d_in[1];
    const float* w1a = (const float*)d_in[2];
    const float* b1a = (const float*)d_in[3];
    const float* w1b = (const float*)d_in[4];
    const float* b1b = (const float*)d_in[5];
    const float* wna = (const float*)d_in[6];
    const float* bna = (const float*)d_in[7];
    const float* wnb = (const float*)d_in[8];
    const float* bnb = (const float*)d_in[9];
    const float* wua = (const float*)d_in[10];
    const float* bua = (const float*)d_in[11];
    const float* wub = (const float*)d_in[12];
    const float* bub = (const float*)d_in[13];
    const int* atr_row = (const int*)d_in[14];
    const int* atr_col = (const int*)d_in[15];
    const int* usr_row = (const int*)d_in[16];
    const int* usr_col = (const int*)d_in[17];

    char* ws = (char*)d_ws;
    size_t o = 0;
    auto alloc = [&](size_t bytes) { void* p = ws + o; o += (bytes + 255) & ~(size_t)255; return p; };

    int* cnt_atr   = (int*)alloc(N_ATR * 4);
    int* cnt_news  = (int*)alloc(N_NEWS * 4);
    int* arena_cnt = (int*)alloc(P_USR * 4);
    size_t zero_bytes = o;
    int* cnt_usr   = (int*)alloc((size_t)N_USERS * 4);
    int* start_usr = (int*)alloc((size_t)N_USERS * 4);
    int* ids_atr  = (int*)alloc((size_t)N_ATR * ACAP * 4);
    int* ids_news = (int*)alloc((size_t)N_NEWS * NCAP * 4);
    int* ids_usr  = (int*)alloc((size_t)P_USR * ACAPP * 4);
    unsigned long long* arena = (unsigned long long*)alloc((size_t)P_USR * ACAPP * 8);
    ushort* agr_atr_b  = (ushort*)alloc((size_t)N_ATR * 768 * 2);
    ushort* h_atr_b    = (ushort*)alloc((size_t)N_ATR * 256 * 2);
    ushort* atr_feats_b= (ushort*)alloc((size_t)N_ATR * 128 * 2);
    ushort* agr_news_b = (ushort*)alloc((size_t)N_NEWS * 128 * 2);
    ushort* agr_usr_b  = (ushort*)alloc((size_t)N_USERS * 128 * 2);
    ushort* out_news_b = (ushort*)alloc((size_t)N_NEWS * 128 * 2);
    ushort* h_buf      = (ushort*)alloc((size_t)N_NEWS * 512 * 2);
    ushort* w1at = (ushort*)alloc((size_t)256 * 768 * 2);
    ushort* w1bt = (ushort*)alloc((size_t)128 * 256 * 2);
    ushort* wnat = (ushort*)alloc((size_t)512 * 896 * 2);
    ushort* wnbt = (ushort*)alloc((size_t)128 * 512 * 2);
    ushort* wuat = (ushort*)alloc((size_t)256 * 256 * 2);
    ushort* wubt = (ushort*)alloc((size_t)128 * 256 * 2);

    float* out = (float*)d_out;
    float* out_users = out + (size_t)N_NEWS * 128;

    hipMemsetAsync(cnt_atr, 0, zero_bytes, stream);

    // ---- prep: sort + fill + weight transposes ----
    {
        PrepArgs A;
        A.atr_row = atr_row; A.atr_col = atr_col;
        A.usr_row = usr_row; A.usr_col = usr_col;
        A.cnt_atr = cnt_atr; A.cnt_news = cnt_news; A.arena_cnt = arena_cnt;
        A.ids_atr = ids_atr; A.ids_news = ids_news;
        A.arena = arena;
        A.pa = (E_USR + EBLK_A - 1) / EBLK_A;     // 489
        A.fa = 25;
        int acc2 = 0;
        auto add = [&](int i, const float* s, ushort* d, int R, int C) {
            acc2 += (C / 32) * (R / 32);
            A.j[i] = TrJob{s, d, R, C, acc2};
        };
        add(0, w1a, w1at, 768, 256);
        add(1, w1b, w1bt, 256, 128);
        add(2, wna, wnat, 896, 512);
        add(3, wnb, wnbt, 512, 128);
        add(4, wua, wuat, 256, 256);
        add(5, wub, wubt, 256, 128);
        A.tr = acc2;
        prep_k<<<A.pa + A.fa + A.tr, 256, 0, stream>>>(A);
    }

    // ---- mid: usr pass B (CSR) + gather768 (f32 direct) ----
    {
        MidArgs M;
        M.arena = arena; M.arena_cnt = arena_cnt;
        M.cnt_usr = cnt_usr; M.start_usr = start_usr; M.ids_usr = ids_usr;
        M.news_x = news_x; M.ids_atr = ids_atr; M.cnt_atr = cnt_atr;
        M.agr_atr_b = agr_atr_b;
        mid_k<<<P_USR + N_ATR, 256, 0, stream>>>(M);
    }

    // attr MLP
    gemm5_k<12, 12, true, 0, 2, false><<<16, 256, 0, stream>>>(
        agr_atr_b, nullptr, w1at, b1a, nullptr, h_atr_b, N_ATR, 256);
    gemm5_k<4, 4, false, 0, 1, false><<<8, 256, 0, stream>>>(
        h_atr_b, nullptr, w1bt, b1b, nullptr, atr_feats_b, N_ATR, 128);
    gather128c_k<NCAP><<<(N_NEWS + 7) / 8, 256, 0, stream>>>(
        atr_feats_b, ids_news, cnt_news, agr_news_b, N_NEWS);

    // news MLP (A1 = f32 news_x, reg-staged)
    gemm5_k<14, 12, true, 0, 4, true><<<391 * 4, 256, 0, stream>>>(
        (const ushort*)news_x, agr_news_b, wnat, bna, nullptr, h_buf, N_NEWS, 512);
    gemm5_k<8, 8, false, 2, 1, false><<<391, 256, 0, stream>>>(
        h_buf, nullptr, wnbt, bnb, out, out_news_b, N_NEWS, 128);

    // users pipeline (fused MLP, f32 users_x)
    gather128s_k<<<(N_USERS + 7) / 8, 256, 0, stream>>>(
        out_news_b, ids_usr, start_usr, cnt_usr, agr_usr_b, N_USERS);
    mlp_users_fused<<<(N_USERS + 63) / 64, 256, 0, stream>>>(
        users_x, agr_usr_b, wuat, bua, wubt, bub, out_users, N_USERS);
}

// Round 18
// 404.093 us; speedup vs baseline: 1.1403x; 1.1403x over previous
//
#include <hip/hip_runtime.h>

#define N_NEWS 50000
#define N_USERS 100000
#define N_ATR 1000
#define E_ATR 100000
#define E_USR 2000000
#define EPSF 1e-8f

#define ACAP 192   // attr bucket capacity
#define NCAP 24    // news bucket capacity
#define P_USR 250  // user partitions (coarse sort)
#define UPP 400    // users per partition
#define ACAPP 9216 // arena capacity per partition
#define EBLK_A 4096

typedef short s16x8 __attribute__((ext_vector_type(8)));
typedef float f32x4 __attribute__((ext_vector_type(4)));

__device__ inline ushort f2bf(float f) {
    uint u = __float_as_uint(f);
    u += 0x7fffu + ((u >> 16) & 1u);
    return (ushort)(u >> 16);
}
__device__ inline float bflo(uint v) { return __uint_as_float(v << 16); }
__device__ inline float bfhi(uint v) { return __uint_as_float(v & 0xffff0000u); }
__device__ inline float fast_tanh(float x) {
    x = fminf(fmaxf(x, -15.0f), 15.0f);
    float e = __expf(2.0f * x);
    return (e - 1.0f) / (e + 1.0f);
}

struct TrJob { const float* src; ushort* dst; int R, C, blkEnd; };

// ================== fused prep mega-kernel (R14 structure, best known) =======
struct PrepArgs {
    const int *atr_row, *atr_col, *usr_row, *usr_col;
    int *cnt_atr, *cnt_news, *arena_cnt;
    int *ids_atr, *ids_news;
    unsigned long long* arena;
    const float *news_x, *users_x;
    ushort *news_bf, *users_bf;
    int pa, fa, tr, n1, n2;
    TrJob j[6];
};

__global__ void prep_k(PrepArgs A) {
    __shared__ float tile[32][33];
    __shared__ int cloc[256], cscn[256], sexc[256], cbase[256];
    __shared__ ushort stageI[EBLK_A];
    int b = blockIdx.x;
    int t = threadIdx.x;
    if (b < A.pa) {
        // ---- usr pass A: LDS counting-sort of edge indices + coalesced flush ----
        cloc[t] = 0;
        __syncthreads();
        int base = b * EBLK_A;
        int endE = base + EBLK_A; if (endE > E_USR) endE = E_USR;
        int n = endE - base;
        for (int e = base + t; e < endE; e += 256)
            atomicAdd(&cloc[A.usr_col[e] / UPP], 1);
        __syncthreads();
        cscn[t] = cloc[t];
        __syncthreads();
        for (int off = 1; off < 256; off <<= 1) {
            int v = (t >= off) ? cscn[t - off] : 0;
            __syncthreads();
            cscn[t] += v;
            __syncthreads();
        }
        sexc[t] = cscn[t] - cloc[t];
        if (t < P_USR) cbase[t] = atomicAdd(&A.arena_cnt[t], cloc[t]);
        cloc[t] = 0;
        __syncthreads();
        for (int e = base + t; e < endE; e += 256) {
            int p = A.usr_col[e] / UPP;
            int off = atomicAdd(&cloc[p], 1);
            stageI[sexc[p] + off] = (ushort)(e - base);
        }
        __syncthreads();
        for (int i = t; i < n; i += 256) {
            int e = base + stageI[i];
            int c = A.usr_col[e];
            int r = A.usr_row[e];
            int p = c / UPP;
            int dst = cbase[p] + (i - sexc[p]);
            if (dst < ACAPP)
                A.arena[(size_t)p * ACAPP + dst] =
                    ((unsigned long long)(uint)c << 32) | (uint)r;
        }
        return;
    }
    b -= A.pa;
    if (b < A.fa) {
        // ---- atr + news bucket fill ----
        int total = 2 * E_ATR;
        int per = (total + A.fa - 1) / A.fa;
        int base = b * per;
        int endE = base + per; if (endE > total) endE = total;
        for (int e = base + t; e < endE; e += 256) {
            if (e < E_ATR) {
                int c = A.atr_col[e];
                int slot = atomicAdd(&A.cnt_atr[c], 1);
                if (slot < ACAP) A.ids_atr[(size_t)c * ACAP + slot] = A.atr_row[e];
            } else {
                int e2 = e - E_ATR;
                int r = A.atr_row[e2];
                int slot = atomicAdd(&A.cnt_news[r], 1);
                if (slot < NCAP) A.ids_news[(size_t)r * NCAP + slot] = A.atr_col[e2];
            }
        }
        return;
    }
    b -= A.fa;
    if (b < A.tr) {
        // ---- weight transpose+cvt ----
        int ji = 0;
        while (b >= A.j[ji].blkEnd) ++ji;
        const TrJob& J = A.j[ji];
        int lb = b - (ji ? A.j[ji - 1].blkEnd : 0);
        int ctiles = J.C / 32;
        int bc = (lb % ctiles) * 32, br = (lb / ctiles) * 32;
        int tx = t & 31, ty = t >> 5;
        for (int i = 0; i < 4; ++i)
            tile[ty + i * 8][tx] = J.src[(size_t)(br + ty + i * 8) * J.C + bc + tx];
        __syncthreads();
        for (int i = 0; i < 4; ++i)
            J.dst[(size_t)(bc + ty + i * 8) * J.R + br + tx] = f2bf(tile[tx][ty + i * 8]);
        return;
    }
    b -= A.tr;
    // ---- bf16 cvt: one float4 per thread ----
    int i = b * 256 + t;
    const float* src; ushort* dst;
    if (i < A.n1) { src = A.news_x; dst = A.news_bf; }
    else          { i -= A.n1; if (i >= A.n2) return; src = A.users_x; dst = A.users_bf; }
    float4 a = ((const float4*)src)[i];
    uint2 v;
    v.x = (uint)f2bf(a.x) | ((uint)f2bf(a.y) << 16);
    v.y = (uint)f2bf(a.z) | ((uint)f2bf(a.w) << 16);
    ((uint2*)dst)[i] = v;
}

// ============ mid kernel: usr pass B (per-partition CSR) + gather768 ============
struct MidArgs {
    const unsigned long long* arena;
    const int* arena_cnt;
    int *cnt_usr, *start_usr, *ids_usr;
    const ushort* news_bf;
    const int* ids_atr;
    const int* cnt_atr;
    ushort* agr_atr_b;
};

__global__ void mid_k(MidArgs M) {
    __shared__ int cnt[512];
    __shared__ int scn[512];
    int b = blockIdx.x;
    int t = threadIdx.x;
    if (b < P_USR) {
        int p = b;
        int nA = M.arena_cnt[p]; if (nA > ACAPP) nA = ACAPP;
        const unsigned long long* ar = M.arena + (size_t)p * ACAPP;
        cnt[t] = 0; cnt[t + 256] = 0;
        __syncthreads();
        for (int i = t; i < nA; i += 256)
            atomicAdd(&cnt[(int)(ar[i] >> 32) - p * UPP], 1);
        __syncthreads();
        scn[t] = cnt[t]; scn[t + 256] = cnt[t + 256];
        __syncthreads();
        for (int off = 1; off < 512; off <<= 1) {
            int v0 = (t >= off) ? scn[t - off] : 0;
            int v1 = ((t + 256) >= off) ? scn[t + 256 - off] : 0;
            __syncthreads();
            scn[t] += v0; scn[t + 256] += v1;
            __syncthreads();
        }
        for (int i = t; i < UPP; i += 256) {
            int u = p * UPP + i;
            M.cnt_usr[u] = cnt[i];
            M.start_usr[u] = p * ACAPP + (scn[i] - cnt[i]);
        }
        __syncthreads();
        for (int i = t; i < UPP; i += 256) cnt[i] = scn[i] - cnt[i];
        __syncthreads();
        for (int i = t; i < nA; i += 256) {
            unsigned long long v = ar[i];
            int c = (int)(v >> 32);
            int off = atomicAdd(&cnt[c - p * UPP], 1);
            M.ids_usr[(size_t)p * ACAPP + off] = (int)(v & 0xffffffffu);
        }
        return;
    }
    b -= P_USR;
    // ---- gather 768-dim news -> attr (bucket layout), 4-way ILP ----
    int u = b;
    int dc = M.cnt_atr[u];
    int d = dc < ACAP ? dc : ACAP;
    const int* bp = M.ids_atr + (size_t)u * ACAP;
    const ushort* src = M.news_bf;
    float a0 = 0.f, a1 = 0.f, a2 = 0.f, a3 = 0.f;
    int i = 0;
    for (; i + 3 < d; i += 4) {
        const uint* r0 = (const uint*)(src + (size_t)bp[i] * 768);
        const uint* r1 = (const uint*)(src + (size_t)bp[i + 1] * 768);
        const uint* r2 = (const uint*)(src + (size_t)bp[i + 2] * 768);
        const uint* r3 = (const uint*)(src + (size_t)bp[i + 3] * 768);
        uint v0 = r0[t], v1 = r1[t], v2 = r2[t], v3 = r3[t];
        a0 += bflo(v0) + bflo(v1) + bflo(v2) + bflo(v3);
        a1 += bfhi(v0) + bfhi(v1) + bfhi(v2) + bfhi(v3);
        if (t < 128) {
            uint w0 = r0[t + 256], w1 = r1[t + 256], w2 = r2[t + 256], w3 = r3[t + 256];
            a2 += bflo(w0) + bflo(w1) + bflo(w2) + bflo(w3);
            a3 += bfhi(w0) + bfhi(w1) + bfhi(w2) + bfhi(w3);
        }
    }
    for (; i < d; ++i) {
        const uint* r0 = (const uint*)(src + (size_t)bp[i] * 768);
        uint v0 = r0[t];
        a0 += bflo(v0); a1 += bfhi(v0);
        if (t < 128) {
            uint v1 = r0[t + 256];
            a2 += bflo(v1); a3 += bfhi(v1);
        }
    }
    float inv = 1.0f / ((float)dc + EPSF);
    uint* dst = (uint*)(M.agr_atr_b + (size_t)u * 768);
    dst[t] = (uint)f2bf(a0 * inv) | ((uint)f2bf(a1 * inv) << 16);
    if (t < 128)
        dst[256 + t] = (uint)f2bf(a2 * inv) | ((uint)f2bf(a3 * inv) << 16);
}

// ------- gather 128-dim (bucket layout), 32 lanes/dest (2 dests/wave) -------
template<int CAP>
__global__ void gather128c_k(const ushort* __restrict__ srcp, const int* __restrict__ ids,
                             const int* __restrict__ cnt, ushort* __restrict__ agr, int n) {
    int u = blockIdx.x * 8 + (threadIdx.x >> 5);
    if (u >= n) return;
    int lane = threadIdx.x & 31;
    int dc = cnt[u];
    int d = dc < CAP ? dc : CAP;
    const int* bp = ids + (size_t)u * CAP;
    float a0 = 0.f, a1 = 0.f, a2 = 0.f, a3 = 0.f;
    int i = 0;
    for (; i + 3 < d; i += 4) {
        int s0 = bp[i], s1 = bp[i + 1], s2 = bp[i + 2], s3 = bp[i + 3];
        uint2 v0 = *((const uint2*)(srcp + (size_t)s0 * 128) + lane);
        uint2 v1 = *((const uint2*)(srcp + (size_t)s1 * 128) + lane);
        uint2 v2 = *((const uint2*)(srcp + (size_t)s2 * 128) + lane);
        uint2 v3 = *((const uint2*)(srcp + (size_t)s3 * 128) + lane);
        a0 += bflo(v0.x) + bflo(v1.x) + bflo(v2.x) + bflo(v3.x);
        a1 += bfhi(v0.x) + bfhi(v1.x) + bfhi(v2.x) + bfhi(v3.x);
        a2 += bflo(v0.y) + bflo(v1.y) + bflo(v2.y) + bflo(v3.y);
        a3 += bfhi(v0.y) + bfhi(v1.y) + bfhi(v2.y) + bfhi(v3.y);
    }
    for (; i < d; ++i) {
        uint2 v0 = *((const uint2*)(srcp + (size_t)bp[i] * 128) + lane);
        a0 += bflo(v0.x); a1 += bfhi(v0.x);
        a2 += bflo(v0.y); a3 += bfhi(v0.y);
    }
    float inv = 1.0f / ((float)dc + EPSF);
    uint2 packed;
    packed.x = (uint)f2bf(a0 * inv) | ((uint)f2bf(a1 * inv) << 16);
    packed.y = (uint)f2bf(a2 * inv) | ((uint)f2bf(a3 * inv) << 16);
    *((uint2*)(agr + (size_t)u * 128) + lane) = packed;
}

// ------- gather 128-dim (CSR layout), 32 lanes/dest, 8-way load ILP -------
__global__ void gather128s_k(const ushort* __restrict__ srcp, const int* __restrict__ ids,
                             const int* __restrict__ start, const int* __restrict__ cnt,
                             ushort* __restrict__ agr, int n) {
    int u = blockIdx.x * 8 + (threadIdx.x >> 5);
    if (u >= n) return;
    int lane = threadIdx.x & 31;
    int d = cnt[u];
    const int* bp = ids + start[u];
    float a0 = 0.f, a1 = 0.f, a2 = 0.f, a3 = 0.f;
    int i = 0;
    for (; i + 7 < d; i += 8) {
        uint2 v0 = *((const uint2*)(srcp + (size_t)bp[i] * 128) + lane);
        uint2 v1 = *((const uint2*)(srcp + (size_t)bp[i + 1] * 128) + lane);
        uint2 v2 = *((const uint2*)(srcp + (size_t)bp[i + 2] * 128) + lane);
        uint2 v3 = *((const uint2*)(srcp + (size_t)bp[i + 3] * 128) + lane);
        uint2 v4 = *((const uint2*)(srcp + (size_t)bp[i + 4] * 128) + lane);
        uint2 v5 = *((const uint2*)(srcp + (size_t)bp[i + 5] * 128) + lane);
        uint2 v6 = *((const uint2*)(srcp + (size_t)bp[i + 6] * 128) + lane);
        uint2 v7 = *((const uint2*)(srcp + (size_t)bp[i + 7] * 128) + lane);
        a0 += bflo(v0.x) + bflo(v1.x) + bflo(v2.x) + bflo(v3.x)
            + bflo(v4.x) + bflo(v5.x) + bflo(v6.x) + bflo(v7.x);
        a1 += bfhi(v0.x) + bfhi(v1.x) + bfhi(v2.x) + bfhi(v3.x)
            + bfhi(v4.x) + bfhi(v5.x) + bfhi(v6.x) + bfhi(v7.x);
        a2 += bflo(v0.y) + bflo(v1.y) + bflo(v2.y) + bflo(v3.y)
            + bflo(v4.y) + bflo(v5.y) + bflo(v6.y) + bflo(v7.y);
        a3 += bfhi(v0.y) + bfhi(v1.y) + bfhi(v2.y) + bfhi(v3.y)
            + bfhi(v4.y) + bfhi(v5.y) + bfhi(v6.y) + bfhi(v7.y);
    }
    for (; i < d; ++i) {
        uint2 v0 = *((const uint2*)(srcp + (size_t)bp[i] * 128) + lane);
        a0 += bflo(v0.x); a1 += bfhi(v0.x);
        a2 += bflo(v0.y); a3 += bfhi(v0.y);
    }
    float inv = 1.0f / ((float)d + EPSF);
    uint2 packed;
    packed.x = (uint)f2bf(a0 * inv) | ((uint)f2bf(a1 * inv) << 16);
    packed.y = (uint)f2bf(a2 * inv) | ((uint)f2bf(a3 * inv) << 16);
    *((uint2*)(agr + (size_t)u * 128) + lane) = packed;
}

// ================= m97-style MFMA GEMM (XCD-swizzled 1-D grid) =================
template<int NS, int NS1, bool TANH, int OMODE, int GY>
__launch_bounds__(256, 3)
__global__ void gemm5_k(const ushort* __restrict__ A1, const ushort* __restrict__ A2,
                        const ushort* __restrict__ Bt, const float* __restrict__ bias,
                        float* __restrict__ outf, ushort* __restrict__ outb,
                        int M, int N) {
    __shared__ __align__(16) char lds[32768];
    const int t = threadIdx.x;
    const int w = t >> 6, l = t & 63, lr = l & 15, lk = l >> 4;
    const int wm = w >> 1, wn = w & 1;
    int nwg = gridDim.x;
    int q = nwg >> 3, r = nwg & 7;
    int xcd = blockIdx.x & 7, idx = blockIdx.x >> 3;
    int fid = (xcd < r) ? xcd * (q + 1) + idx : r * (q + 1) + (xcd - r) * q + idx;
    constexpr int LG = (GY == 4) ? 2 : (GY == 2) ? 1 : 0;
    const int row0 = (fid >> LG) * 128;
    const int col0 = (fid & (GY - 1)) * 128;
    constexpr int A1RB = NS1 * 128;
    constexpr int A2RB = (NS - NS1) * 128;
    constexpr int BRB = NS * 128;

    auto stage = [&](int s) {
        const char* abase; int arb, soff;
        if (s < NS1) { abase = (const char*)A1; arb = A1RB; soff = s * 128; }
        else         { abase = (const char*)A2; arb = A2RB; soff = (s - NS1) * 128; }
#pragma unroll
        for (int i = 0; i < 4; ++i) {
            int chunk = i * 256 + w * 64 + l;
            int row = chunk >> 3, sub = chunk & 7;
            int rg = row0 + row; if (rg >= M) rg = M - 1;
            const char* src = abase + (size_t)rg * arb + soff + ((sub * 16) ^ ((row & 7) << 4));
            __builtin_amdgcn_global_load_lds(
                (const __attribute__((address_space(1))) unsigned int*)src,
                (__attribute__((address_space(3))) unsigned int*)(lds + i * 4096 + w * 1024),
                16, 0, 0);
        }
#pragma unroll
        for (int i = 0; i < 4; ++i) {
            int chunk = i * 256 + w * 64 + l;
            int row = chunk >> 3, sub = chunk & 7;
            const char* src = (const char*)Bt + (size_t)(col0 + row) * BRB + s * 128
                              + ((sub * 16) ^ ((row & 7) << 4));
            __builtin_amdgcn_global_load_lds(
                (const __attribute__((address_space(1))) unsigned int*)src,
                (__attribute__((address_space(3))) unsigned int*)(lds + 16384 + i * 4096 + w * 1024),
                16, 0, 0);
        }
    };

    f32x4 acc[4][4];
#pragma unroll
    for (int i = 0; i < 4; ++i)
#pragma unroll
        for (int j = 0; j < 4; ++j) acc[i][j] = (f32x4)0.f;

    stage(0);
    for (int s = 0; s < NS; ++s) {
        __syncthreads();
#pragma unroll
        for (int ks = 0; ks < 2; ++ks) {
            s16x8 af[4], bf[4];
#pragma unroll
            for (int rt = 0; rt < 4; ++rt) {
                int rr = wm * 64 + rt * 16 + lr;
                af[rt] = *(const s16x8*)(lds + rr * 128 + ((ks * 64 + lk * 16) ^ ((rr & 7) << 4)));
            }
#pragma unroll
            for (int ct = 0; ct < 4; ++ct) {
                int c = wn * 64 + ct * 16 + lr;
                bf[ct] = *(const s16x8*)(lds + 16384 + c * 128 + ((ks * 64 + lk * 16) ^ ((c & 7) << 4)));
            }
#pragma unroll
            for (int rt = 0; rt < 4; ++rt)
#pragma unroll
                for (int ct = 0; ct < 4; ++ct)
                    acc[rt][ct] = __builtin_amdgcn_mfma_f32_16x16x32_bf16(
                        af[rt], bf[ct], acc[rt][ct], 0, 0, 0);
        }
        __syncthreads();
        if (s + 1 < NS) stage(s + 1);
    }

    if (OMODE == 0) {
#pragma unroll
        for (int rt = 0; rt < 4; ++rt)
#pragma unroll
            for (int ct = 0; ct < 4; ++ct) {
                int c = wn * 64 + ct * 16 + lr;
                float bs = bias[col0 + c];
#pragma unroll
                for (int r4 = 0; r4 < 4; ++r4) {
                    int rr = wm * 64 + rt * 16 + lk * 4 + r4;
                    float v = acc[rt][ct][r4] + bs;
                    if (TANH) v = fast_tanh(v);
                    *(ushort*)(lds + rr * 256 + ((c * 2) ^ ((rr & 7) << 4))) = f2bf(v);
                }
            }
        __syncthreads();
#pragma unroll
        for (int i = 0; i < 8; ++i) {
            int chunk = i * 256 + t;
            int rr = chunk >> 4, cb = (chunk & 15) * 16;
            int rg = row0 + rr;
            if (rg < M)
                *(float4*)((char*)outb + (size_t)rg * (N * 2) + col0 * 2 + cb) =
                    *(const float4*)(lds + rr * 256 + (cb ^ ((rr & 7) << 4)));
        }
    } else {
#pragma unroll
        for (int rt = 0; rt < 4; ++rt)
#pragma unroll
            for (int ct = 0; ct < 4; ++ct) {
                int c = col0 + wn * 64 + ct * 16 + lr;
                float bs = bias[c];
#pragma unroll
                for (int r4 = 0; r4 < 4; ++r4) {
                    int rg = row0 + wm * 64 + rt * 16 + lk * 4 + r4;
                    if (rg < M) {
                        float v = acc[rt][ct][r4] + bs;
                        if (TANH) v = fast_tanh(v);
                        outf[(size_t)rg * N + c] = v;
                        if (OMODE == 2) outb[(size_t)rg * N + c] = f2bf(v);
                    }
                }
            }
    }
}

extern "C" void kernel_launch(void* const* d_in, const int* in_sizes, int n_in,
                              void* d_out, int out_size, void* d_ws, size_t ws_size,
                              hipStream_t stream) {
    const float* news_x  = (const float*)d_in[0];
    const float* users_x = (const float*)d_in[1];
    const float* w1a = (const float*)d_in[2];
    const float* b1a = (const float*)d_in[3];
    const float* w1b = (const float*)d_in[4];
    const float* b1b = (const float*)d_in[5];
    const float* wna = (const float*)d_in[6];
    const float* bna = (const float*)d_in[7];
    const float* wnb = (const float*)d_in[8];
    const float* bnb = (const float*)d_in[9];
    const float* wua = (const float*)d_in[10];
    const float* bua = (const float*)d_in[11];
    const float* wub = (const float*)d_in[12];
    const float* bub = (const float*)d_in[13];
    const int* atr_row = (const int*)d_in[14];
    const int* atr_col = (const int*)d_in[15];
    const int* usr_row = (const int*)d_in[16];
    const int* usr_col = (const int*)d_in[17];

    char* ws = (char*)d_ws;
    size_t o = 0;
    auto alloc = [&](size_t bytes) { void* p = ws + o; o += (bytes + 255) & ~(size_t)255; return p; };

    int* cnt_atr   = (int*)alloc(N_ATR * 4);
    int* cnt_news  = (int*)alloc(N_NEWS * 4);
    int* arena_cnt = (int*)alloc(P_USR * 4);
    size_t zero_bytes = o;
    int* cnt_usr   = (int*)alloc((size_t)N_USERS * 4);
    int* start_usr = (int*)alloc((size_t)N_USERS * 4);
    int* ids_atr  = (int*)alloc((size_t)N_ATR * ACAP * 4);
    int* ids_news = (int*)alloc((size_t)N_NEWS * NCAP * 4);
    int* ids_usr  = (int*)alloc((size_t)P_USR * ACAPP * 4);
    unsigned long long* arena = (unsigned long long*)alloc((size_t)P_USR * ACAPP * 8);
    ushort* news_bf    = (ushort*)alloc((size_t)N_NEWS * 768 * 2);
    ushort* users_bf   = (ushort*)alloc((size_t)N_USERS * 128 * 2);
    ushort* agr_atr_b  = (ushort*)alloc((size_t)N_ATR * 768 * 2);
    ushort* h_atr_b    = (ushort*)alloc((size_t)N_ATR * 256 * 2);
    ushort* atr_feats_b= (ushort*)alloc((size_t)N_ATR * 128 * 2);
    ushort* agr_news_b = (ushort*)alloc((size_t)N_NEWS * 128 * 2);
    ushort* agr_usr_b  = (ushort*)alloc((size_t)N_USERS * 128 * 2);
    ushort* out_news_b = (ushort*)alloc((size_t)N_NEWS * 128 * 2);
    ushort* h_buf      = (ushort*)alloc((size_t)N_USERS * 256 * 2);
    ushort* w1at = (ushort*)alloc((size_t)256 * 768 * 2);
    ushort* w1bt = (ushort*)alloc((size_t)128 * 256 * 2);
    ushort* wnat = (ushort*)alloc((size_t)512 * 896 * 2);
    ushort* wnbt = (ushort*)alloc((size_t)128 * 512 * 2);
    ushort* wuat = (ushort*)alloc((size_t)256 * 256 * 2);
    ushort* wubt = (ushort*)alloc((size_t)128 * 256 * 2);

    float* out = (float*)d_out;
    float* out_users = out + (size_t)N_NEWS * 128;

    hipMemsetAsync(cnt_atr, 0, zero_bytes, stream);

    // ---- fused prep ----
    {
        PrepArgs A;
        A.atr_row = atr_row; A.atr_col = atr_col;
        A.usr_row = usr_row; A.usr_col = usr_col;
        A.cnt_atr = cnt_atr; A.cnt_news = cnt_news; A.arena_cnt = arena_cnt;
        A.ids_atr = ids_atr; A.ids_news = ids_news;
        A.arena = arena;
        A.news_x = news_x; A.users_x = users_x;
        A.news_bf = news_bf; A.users_bf = users_bf;
        A.pa = (E_USR + EBLK_A - 1) / EBLK_A;     // 489
        A.fa = 25;
        A.n1 = N_NEWS * 768 / 4;
        A.n2 = N_USERS * 128 / 4;
        int acc2 = 0;
        auto add = [&](int i, const float* s, ushort* d, int R, int C) {
            acc2 += (C / 32) * (R / 32);
            A.j[i] = TrJob{s, d, R, C, acc2};
        };
        add(0, w1a, w1at, 768, 256);
        add(1, w1b, w1bt, 256, 128);
        add(2, wna, wnat, 896, 512);
        add(3, wnb, wnbt, 512, 128);
        add(4, wua, wuat, 256, 256);
        add(5, wub, wubt, 256, 128);
        A.tr = acc2;
        int cvt_blk = (A.n1 + A.n2 + 255) / 256;
        prep_k<<<A.pa + A.fa + A.tr + cvt_blk, 256, 0, stream>>>(A);
    }

    // ---- mid: usr pass B (CSR) + gather768 ----
    {
        MidArgs M;
        M.arena = arena; M.arena_cnt = arena_cnt;
        M.cnt_usr = cnt_usr; M.start_usr = start_usr; M.ids_usr = ids_usr;
        M.news_bf = news_bf; M.ids_atr = ids_atr; M.cnt_atr = cnt_atr;
        M.agr_atr_b = agr_atr_b;
        mid_k<<<P_USR + N_ATR, 256, 0, stream>>>(M);
    }

    // attr MLP
    gemm5_k<12, 12, true, 0, 2><<<16, 256, 0, stream>>>(
        agr_atr_b, nullptr, w1at, b1a, nullptr, h_atr_b, N_ATR, 256);
    gemm5_k<4, 4, false, 0, 1><<<8, 256, 0, stream>>>(
        h_atr_b, nullptr, w1bt, b1b, nullptr, atr_feats_b, N_ATR, 128);
    gather128c_k<NCAP><<<(N_NEWS + 7) / 8, 256, 0, stream>>>(
        atr_feats_b, ids_news, cnt_news, agr_news_b, N_NEWS);

    // news MLP
    gemm5_k<14, 12, true, 0, 4><<<391 * 4, 256, 0, stream>>>(
        news_bf, agr_news_b, wnat, bna, nullptr, h_buf, N_NEWS, 512);
    gemm5_k<8, 8, false, 2, 1><<<391, 256, 0, stream>>>(
        h_buf, nullptr, wnbt, bnb, out, out_news_b, N_NEWS, 128);

    // users pipeline
    gather128s_k<<<(N_USERS + 7) / 8, 256, 0, stream>>>(
        out_news_b, ids_usr, start_usr, cnt_usr, agr_usr_b, N_USERS);
    gemm5_k<4, 2, true, 0, 2><<<782 * 2, 256, 0, stream>>>(
        users_bf, agr_usr_b, wuat, bua, nullptr, h_buf, N_USERS, 256);
    gemm5_k<4, 4, false, 1, 1><<<782, 256, 0, stream>>>(
        h_buf, nullptr, wubt, bub, out_users, nullptr, N_USERS, 128);
}

// Round 19
// 402.768 us; speedup vs baseline: 1.1441x; 1.0033x over previous
//
#include <hip/hip_runtime.h>

#define N_NEWS 50000
#define N_USERS 100000
#define N_ATR 1000
#define E_ATR 100000
#define E_USR 2000000
#define EPSF 1e-8f

#define ACAP 192   // attr bucket capacity
#define NCAP 24    // news bucket capacity
#define P_USR 250  // user partitions (coarse sort)
#define UPP 400    // users per partition
#define ACAPP 9216 // arena capacity per partition
#define EBLK_A 4096

typedef short s16x8 __attribute__((ext_vector_type(8)));
typedef float f32x4 __attribute__((ext_vector_type(4)));

__device__ inline ushort f2bf(float f) {
    uint u = __float_as_uint(f);
    u += 0x7fffu + ((u >> 16) & 1u);
    return (ushort)(u >> 16);
}
__device__ inline float bflo(uint v) { return __uint_as_float(v << 16); }
__device__ inline float bfhi(uint v) { return __uint_as_float(v & 0xffff0000u); }
__device__ inline float fast_tanh(float x) {
    x = fminf(fmaxf(x, -15.0f), 15.0f);
    float e = __expf(2.0f * x);
    return (e - 1.0f) / (e + 1.0f);
}

struct TrJob { const float* src; ushort* dst; int R, C, blkEnd; };

// ================== fused prep mega-kernel ==================
// cvt role: LDS-repacked so BOTH loads (16B/lane) and stores (16B/lane) are
// full-width coalesced — tests the hypothesis that the ~2.3 TB/s cvt ceiling
// (R13/R14/R15, all with 8B stores or strided loads) is store-width-bound.
struct PrepArgs {
    const int *atr_row, *atr_col, *usr_row, *usr_col;
    int *cnt_atr, *cnt_news, *arena_cnt;
    int *ids_atr, *ids_news;
    unsigned long long* arena;
    const float *news_x, *users_x;
    ushort *news_bf, *users_bf;
    int pa, fa, tr, n1, n2;   // n1/n2 = cvt TILE counts (512 float4 per tile)
    TrJob j[6];
};

__global__ void prep_k(PrepArgs A) {
    __shared__ float tile[32][33];
    __shared__ int cloc[256], cscn[256], sexc[256], cbase[256];
    __shared__ ushort stageI[EBLK_A];
    int b = blockIdx.x;
    int t = threadIdx.x;
    if (b < A.pa) {
        // ---- usr pass A: LDS counting-sort of edge indices + coalesced flush ----
        cloc[t] = 0;
        __syncthreads();
        int base = b * EBLK_A;
        int endE = base + EBLK_A; if (endE > E_USR) endE = E_USR;
        int n = endE - base;
        for (int e = base + t; e < endE; e += 256)
            atomicAdd(&cloc[A.usr_col[e] / UPP], 1);
        __syncthreads();
        cscn[t] = cloc[t];
        __syncthreads();
        for (int off = 1; off < 256; off <<= 1) {
            int v = (t >= off) ? cscn[t - off] : 0;
            __syncthreads();
            cscn[t] += v;
            __syncthreads();
        }
        sexc[t] = cscn[t] - cloc[t];
        if (t < P_USR) cbase[t] = atomicAdd(&A.arena_cnt[t], cloc[t]);
        cloc[t] = 0;
        __syncthreads();
        for (int e = base + t; e < endE; e += 256) {
            int p = A.usr_col[e] / UPP;
            int off = atomicAdd(&cloc[p], 1);
            stageI[sexc[p] + off] = (ushort)(e - base);
        }
        __syncthreads();
        for (int i = t; i < n; i += 256) {
            int e = base + stageI[i];
            int c = A.usr_col[e];
            int r = A.usr_row[e];
            int p = c / UPP;
            int dst = cbase[p] + (i - sexc[p]);
            if (dst < ACAPP)
                A.arena[(size_t)p * ACAPP + dst] =
                    ((unsigned long long)(uint)c << 32) | (uint)r;
        }
        return;
    }
    b -= A.pa;
    if (b < A.fa) {
        // ---- atr + news bucket fill ----
        int total = 2 * E_ATR;
        int per = (total + A.fa - 1) / A.fa;
        int base = b * per;
        int endE = base + per; if (endE > total) endE = total;
        for (int e = base + t; e < endE; e += 256) {
            if (e < E_ATR) {
                int c = A.atr_col[e];
                int slot = atomicAdd(&A.cnt_atr[c], 1);
                if (slot < ACAP) A.ids_atr[(size_t)c * ACAP + slot] = A.atr_row[e];
            } else {
                int e2 = e - E_ATR;
                int r = A.atr_row[e2];
                int slot = atomicAdd(&A.cnt_news[r], 1);
                if (slot < NCAP) A.ids_news[(size_t)r * NCAP + slot] = A.atr_col[e2];
            }
        }
        return;
    }
    b -= A.fa;
    if (b < A.tr) {
        // ---- weight transpose+cvt ----
        int ji = 0;
        while (b >= A.j[ji].blkEnd) ++ji;
        const TrJob& J = A.j[ji];
        int lb = b - (ji ? A.j[ji - 1].blkEnd : 0);
        int ctiles = J.C / 32;
        int bc = (lb % ctiles) * 32, br = (lb / ctiles) * 32;
        int tx = t & 31, ty = t >> 5;
        for (int i = 0; i < 4; ++i)
            tile[ty + i * 8][tx] = J.src[(size_t)(br + ty + i * 8) * J.C + bc + tx];
        __syncthreads();
        for (int i = 0; i < 4; ++i)
            J.dst[(size_t)(bc + ty + i * 8) * J.R + br + tx] = f2bf(tile[tx][ty + i * 8]);
        return;
    }
    b -= A.tr;
    // ---- bf16 cvt, LDS-repacked: 2x coalesced float4 loads -> LDS ->
    //      1x coalesced uint4 store (16B/lane both directions) ----
    {
        int tid = b;
        const float* src; ushort* dst;
        if (tid < A.n1) { src = A.news_x; dst = A.news_bf; }
        else            { tid -= A.n1; if (tid >= A.n2) return; src = A.users_x; dst = A.users_bf; }
        long tb = (long)tid * 512;            // float4 index base of this tile
        uint2* lbuf = (uint2*)stageI;         // 4KB bounce (aliases sort stage)
#pragma unroll
        for (int j = 0; j < 2; ++j) {
            float4 a = ((const float4*)src)[tb + j * 256 + t];
            uint2 v;
            v.x = (uint)f2bf(a.x) | ((uint)f2bf(a.y) << 16);
            v.y = (uint)f2bf(a.z) | ((uint)f2bf(a.w) << 16);
            lbuf[j * 256 + t] = v;
        }
        __syncthreads();
        ((uint4*)dst)[tb / 2 + t] = ((const uint4*)lbuf)[t];
    }
}

// ============ mid kernel: usr pass B (per-partition CSR) + gather768 ============
struct MidArgs {
    const unsigned long long* arena;
    const int* arena_cnt;
    int *cnt_usr, *start_usr, *ids_usr;
    const ushort* news_bf;
    const int* ids_atr;
    const int* cnt_atr;
    ushort* agr_atr_b;
};

__global__ void mid_k(MidArgs M) {
    __shared__ int cnt[512];
    __shared__ int scn[512];
    int b = blockIdx.x;
    int t = threadIdx.x;
    if (b < P_USR) {
        int p = b;
        int nA = M.arena_cnt[p]; if (nA > ACAPP) nA = ACAPP;
        const unsigned long long* ar = M.arena + (size_t)p * ACAPP;
        cnt[t] = 0; cnt[t + 256] = 0;
        __syncthreads();
        for (int i = t; i < nA; i += 256)
            atomicAdd(&cnt[(int)(ar[i] >> 32) - p * UPP], 1);
        __syncthreads();
        scn[t] = cnt[t]; scn[t + 256] = cnt[t + 256];
        __syncthreads();
        for (int off = 1; off < 512; off <<= 1) {
            int v0 = (t >= off) ? scn[t - off] : 0;
            int v1 = ((t + 256) >= off) ? scn[t + 256 - off] : 0;
            __syncthreads();
            scn[t] += v0; scn[t + 256] += v1;
            __syncthreads();
        }
        for (int i = t; i < UPP; i += 256) {
            int u = p * UPP + i;
            M.cnt_usr[u] = cnt[i];
            M.start_usr[u] = p * ACAPP + (scn[i] - cnt[i]);
        }
        __syncthreads();
        for (int i = t; i < UPP; i += 256) cnt[i] = scn[i] - cnt[i];
        __syncthreads();
        for (int i = t; i < nA; i += 256) {
            unsigned long long v = ar[i];
            int c = (int)(v >> 32);
            int off = atomicAdd(&cnt[c - p * UPP], 1);
            M.ids_usr[(size_t)p * ACAPP + off] = (int)(v & 0xffffffffu);
        }
        return;
    }
    b -= P_USR;
    // ---- gather 768-dim news -> attr (bucket layout), 4-way ILP ----
    int u = b;
    int dc = M.cnt_atr[u];
    int d = dc < ACAP ? dc : ACAP;
    const int* bp = M.ids_atr + (size_t)u * ACAP;
    const ushort* src = M.news_bf;
    float a0 = 0.f, a1 = 0.f, a2 = 0.f, a3 = 0.f;
    int i = 0;
    for (; i + 3 < d; i += 4) {
        const uint* r0 = (const uint*)(src + (size_t)bp[i] * 768);
        const uint* r1 = (const uint*)(src + (size_t)bp[i + 1] * 768);
        const uint* r2 = (const uint*)(src + (size_t)bp[i + 2] * 768);
        const uint* r3 = (const uint*)(src + (size_t)bp[i + 3] * 768);
        uint v0 = r0[t], v1 = r1[t], v2 = r2[t], v3 = r3[t];
        a0 += bflo(v0) + bflo(v1) + bflo(v2) + bflo(v3);
        a1 += bfhi(v0) + bfhi(v1) + bfhi(v2) + bfhi(v3);
        if (t < 128) {
            uint w0 = r0[t + 256], w1 = r1[t + 256], w2 = r2[t + 256], w3 = r3[t + 256];
            a2 += bflo(w0) + bflo(w1) + bflo(w2) + bflo(w3);
            a3 += bfhi(w0) + bfhi(w1) + bfhi(w2) + bfhi(w3);
        }
    }
    for (; i < d; ++i) {
        const uint* r0 = (const uint*)(src + (size_t)bp[i] * 768);
        uint v0 = r0[t];
        a0 += bflo(v0); a1 += bfhi(v0);
        if (t < 128) {
            uint v1 = r0[t + 256];
            a2 += bflo(v1); a3 += bfhi(v1);
        }
    }
    float inv = 1.0f / ((float)dc + EPSF);
    uint* dst = (uint*)(M.agr_atr_b + (size_t)u * 768);
    dst[t] = (uint)f2bf(a0 * inv) | ((uint)f2bf(a1 * inv) << 16);
    if (t < 128)
        dst[256 + t] = (uint)f2bf(a2 * inv) | ((uint)f2bf(a3 * inv) << 16);
}

// ------- gather 128-dim (bucket layout), 32 lanes/dest (2 dests/wave) -------
template<int CAP>
__global__ void gather128c_k(const ushort* __restrict__ srcp, const int* __restrict__ ids,
                             const int* __restrict__ cnt, ushort* __restrict__ agr, int n) {
    int u = blockIdx.x * 8 + (threadIdx.x >> 5);
    if (u >= n) return;
    int lane = threadIdx.x & 31;
    int dc = cnt[u];
    int d = dc < CAP ? dc : CAP;
    const int* bp = ids + (size_t)u * CAP;
    float a0 = 0.f, a1 = 0.f, a2 = 0.f, a3 = 0.f;
    int i = 0;
    for (; i + 3 < d; i += 4) {
        int s0 = bp[i], s1 = bp[i + 1], s2 = bp[i + 2], s3 = bp[i + 3];
        uint2 v0 = *((const uint2*)(srcp + (size_t)s0 * 128) + lane);
        uint2 v1 = *((const uint2*)(srcp + (size_t)s1 * 128) + lane);
        uint2 v2 = *((const uint2*)(srcp + (size_t)s2 * 128) + lane);
        uint2 v3 = *((const uint2*)(srcp + (size_t)s3 * 128) + lane);
        a0 += bflo(v0.x) + bflo(v1.x) + bflo(v2.x) + bflo(v3.x);
        a1 += bfhi(v0.x) + bfhi(v1.x) + bfhi(v2.x) + bfhi(v3.x);
        a2 += bflo(v0.y) + bflo(v1.y) + bflo(v2.y) + bflo(v3.y);
        a3 += bfhi(v0.y) + bfhi(v1.y) + bfhi(v2.y) + bfhi(v3.y);
    }
    for (; i < d; ++i) {
        uint2 v0 = *((const uint2*)(srcp + (size_t)bp[i] * 128) + lane);
        a0 += bflo(v0.x); a1 += bfhi(v0.x);
        a2 += bflo(v0.y); a3 += bfhi(v0.y);
    }
    float inv = 1.0f / ((float)dc + EPSF);
    uint2 packed;
    packed.x = (uint)f2bf(a0 * inv) | ((uint)f2bf(a1 * inv) << 16);
    packed.y = (uint)f2bf(a2 * inv) | ((uint)f2bf(a3 * inv) << 16);
    *((uint2*)(agr + (size_t)u * 128) + lane) = packed;
}

// ------- gather 128-dim (CSR layout), 32 lanes/dest, 8-way load ILP -------
__global__ void gather128s_k(const ushort* __restrict__ srcp, const int* __restrict__ ids,
                             const int* __restrict__ start, const int* __restrict__ cnt,
                             ushort* __restrict__ agr, int n) {
    int u = blockIdx.x * 8 + (threadIdx.x >> 5);
    if (u >= n) return;
    int lane = threadIdx.x & 31;
    int d = cnt[u];
    const int* bp = ids + start[u];
    float a0 = 0.f, a1 = 0.f, a2 = 0.f, a3 = 0.f;
    int i = 0;
    for (; i + 7 < d; i += 8) {
        uint2 v0 = *((const uint2*)(srcp + (size_t)bp[i] * 128) + lane);
        uint2 v1 = *((const uint2*)(srcp + (size_t)bp[i + 1] * 128) + lane);
        uint2 v2 = *((const uint2*)(srcp + (size_t)bp[i + 2] * 128) + lane);
        uint2 v3 = *((const uint2*)(srcp + (size_t)bp[i + 3] * 128) + lane);
        uint2 v4 = *((const uint2*)(srcp + (size_t)bp[i + 4] * 128) + lane);
        uint2 v5 = *((const uint2*)(srcp + (size_t)bp[i + 5] * 128) + lane);
        uint2 v6 = *((const uint2*)(srcp + (size_t)bp[i + 6] * 128) + lane);
        uint2 v7 = *((const uint2*)(srcp + (size_t)bp[i + 7] * 128) + lane);
        a0 += bflo(v0.x) + bflo(v1.x) + bflo(v2.x) + bflo(v3.x)
            + bflo(v4.x) + bflo(v5.x) + bflo(v6.x) + bflo(v7.x);
        a1 += bfhi(v0.x) + bfhi(v1.x) + bfhi(v2.x) + bfhi(v3.x)
            + bfhi(v4.x) + bfhi(v5.x) + bfhi(v6.x) + bfhi(v7.x);
        a2 += bflo(v0.y) + bflo(v1.y) + bflo(v2.y) + bflo(v3.y)
            + bflo(v4.y) + bflo(v5.y) + bflo(v6.y) + bflo(v7.y);
        a3 += bfhi(v0.y) + bfhi(v1.y) + bfhi(v2.y) + bfhi(v3.y)
            + bfhi(v4.y) + bfhi(v5.y) + bfhi(v6.y) + bfhi(v7.y);
    }
    for (; i < d; ++i) {
        uint2 v0 = *((const uint2*)(srcp + (size_t)bp[i] * 128) + lane);
        a0 += bflo(v0.x); a1 += bfhi(v0.x);
        a2 += bflo(v0.y); a3 += bfhi(v0.y);
    }
    float inv = 1.0f / ((float)d + EPSF);
    uint2 packed;
    packed.x = (uint)f2bf(a0 * inv) | ((uint)f2bf(a1 * inv) << 16);
    packed.y = (uint)f2bf(a2 * inv) | ((uint)f2bf(a3 * inv) << 16);
    *((uint2*)(agr + (size_t)u * 128) + lane) = packed;
}

// ================= m97-style MFMA GEMM (XCD-swizzled 1-D grid) =================
template<int NS, int NS1, bool TANH, int OMODE, int GY>
__launch_bounds__(256, 3)
__global__ void gemm5_k(const ushort* __restrict__ A1, const ushort* __restrict__ A2,
                        const ushort* __restrict__ Bt, const float* __restrict__ bias,
                        float* __restrict__ outf, ushort* __restrict__ outb,
                        int M, int N) {
    __shared__ __align__(16) char lds[32768];
    const int t = threadIdx.x;
    const int w = t >> 6, l = t & 63, lr = l & 15, lk = l >> 4;
    const int wm = w >> 1, wn = w & 1;
    int nwg = gridDim.x;
    int q = nwg >> 3, r = nwg & 7;
    int xcd = blockIdx.x & 7, idx = blockIdx.x >> 3;
    int fid = (xcd < r) ? xcd * (q + 1) + idx : r * (q + 1) + (xcd - r) * q + idx;
    constexpr int LG = (GY == 4) ? 2 : (GY == 2) ? 1 : 0;
    const int row0 = (fid >> LG) * 128;
    const int col0 = (fid & (GY - 1)) * 128;
    constexpr int A1RB = NS1 * 128;
    constexpr int A2RB = (NS - NS1) * 128;
    constexpr int BRB = NS * 128;

    auto stage = [&](int s) {
        const char* abase; int arb, soff;
        if (s < NS1) { abase = (const char*)A1; arb = A1RB; soff = s * 128; }
        else         { abase = (const char*)A2; arb = A2RB; soff = (s - NS1) * 128; }
#pragma unroll
        for (int i = 0; i < 4; ++i) {
            int chunk = i * 256 + w * 64 + l;
            int row = chunk >> 3, sub = chunk & 7;
            int rg = row0 + row; if (rg >= M) rg = M - 1;
            const char* src = abase + (size_t)rg * arb + soff + ((sub * 16) ^ ((row & 7) << 4));
            __builtin_amdgcn_global_load_lds(
                (const __attribute__((address_space(1))) unsigned int*)src,
                (__attribute__((address_space(3))) unsigned int*)(lds + i * 4096 + w * 1024),
                16, 0, 0);
        }
#pragma unroll
        for (int i = 0; i < 4; ++i) {
            int chunk = i * 256 + w * 64 + l;
            int row = chunk >> 3, sub = chunk & 7;
            const char* src = (const char*)Bt + (size_t)(col0 + row) * BRB + s * 128
                              + ((sub * 16) ^ ((row & 7) << 4));
            __builtin_amdgcn_global_load_lds(
                (const __attribute__((address_space(1))) unsigned int*)src,
                (__attribute__((address_space(3))) unsigned int*)(lds + 16384 + i * 4096 + w * 1024),
                16, 0, 0);
        }
    };

    f32x4 acc[4][4];
#pragma unroll
    for (int i = 0; i < 4; ++i)
#pragma unroll
        for (int j = 0; j < 4; ++j) acc[i][j] = (f32x4)0.f;

    stage(0);
    for (int s = 0; s < NS; ++s) {
        __syncthreads();
#pragma unroll
        for (int ks = 0; ks < 2; ++ks) {
            s16x8 af[4], bf[4];
#pragma unroll
            for (int rt = 0; rt < 4; ++rt) {
                int rr = wm * 64 + rt * 16 + lr;
                af[rt] = *(const s16x8*)(lds + rr * 128 + ((ks * 64 + lk * 16) ^ ((rr & 7) << 4)));
            }
#pragma unroll
            for (int ct = 0; ct < 4; ++ct) {
                int c = wn * 64 + ct * 16 + lr;
                bf[ct] = *(const s16x8*)(lds + 16384 + c * 128 + ((ks * 64 + lk * 16) ^ ((c & 7) << 4)));
            }
#pragma unroll
            for (int rt = 0; rt < 4; ++rt)
#pragma unroll
                for (int ct = 0; ct < 4; ++ct)
                    acc[rt][ct] = __builtin_amdgcn_mfma_f32_16x16x32_bf16(
                        af[rt], bf[ct], acc[rt][ct], 0, 0, 0);
        }
        __syncthreads();
        if (s + 1 < NS) stage(s + 1);
    }

    if (OMODE == 0) {
#pragma unroll
        for (int rt = 0; rt < 4; ++rt)
#pragma unroll
            for (int ct = 0; ct < 4; ++ct) {
                int c = wn * 64 + ct * 16 + lr;
                float bs = bias[col0 + c];
#pragma unroll
                for (int r4 = 0; r4 < 4; ++r4) {
                    int rr = wm * 64 + rt * 16 + lk * 4 + r4;
                    float v = acc[rt][ct][r4] + bs;
                    if (TANH) v = fast_tanh(v);
                    *(ushort*)(lds + rr * 256 + ((c * 2) ^ ((rr & 7) << 4))) = f2bf(v);
                }
            }
        __syncthreads();
#pragma unroll
        for (int i = 0; i < 8; ++i) {
            int chunk = i * 256 + t;
            int rr = chunk >> 4, cb = (chunk & 15) * 16;
            int rg = row0 + rr;
            if (rg < M)
                *(float4*)((char*)outb + (size_t)rg * (N * 2) + col0 * 2 + cb) =
                    *(const float4*)(lds + rr * 256 + (cb ^ ((rr & 7) << 4)));
        }
    } else {
#pragma unroll
        for (int rt = 0; rt < 4; ++rt)
#pragma unroll
            for (int ct = 0; ct < 4; ++ct) {
                int c = col0 + wn * 64 + ct * 16 + lr;
                float bs = bias[c];
#pragma unroll
                for (int r4 = 0; r4 < 4; ++r4) {
                    int rg = row0 + wm * 64 + rt * 16 + lk * 4 + r4;
                    if (rg < M) {
                        float v = acc[rt][ct][r4] + bs;
                        if (TANH) v = fast_tanh(v);
                        outf[(size_t)rg * N + c] = v;
                        if (OMODE == 2) outb[(size_t)rg * N + c] = f2bf(v);
                    }
                }
            }
    }
}

extern "C" void kernel_launch(void* const* d_in, const int* in_sizes, int n_in,
                              void* d_out, int out_size, void* d_ws, size_t ws_size,
                              hipStream_t stream) {
    const float* news_x  = (const float*)d_in[0];
    const float* users_x = (const float*)d_in[1];
    const float* w1a = (const float*)d_in[2];
    const float* b1a = (const float*)d_in[3];
    const float* w1b = (const float*)d_in[4];
    const float* b1b = (const float*)d_in[5];
    const float* wna = (const float*)d_in[6];
    const float* bna = (const float*)d_in[7];
    const float* wnb = (const float*)d_in[8];
    const float* bnb = (const float*)d_in[9];
    const float* wua = (const float*)d_in[10];
    const float* bua = (const float*)d_in[11];
    const float* wub = (const float*)d_in[12];
    const float* bub = (const float*)d_in[13];
    const int* atr_row = (const int*)d_in[14];
    const int* atr_col = (const int*)d_in[15];
    const int* usr_row = (const int*)d_in[16];
    const int* usr_col = (const int*)d_in[17];

    char* ws = (char*)d_ws;
    size_t o = 0;
    auto alloc = [&](size_t bytes) { void* p = ws + o; o += (bytes + 255) & ~(size_t)255; return p; };

    int* cnt_atr   = (int*)alloc(N_ATR * 4);
    int* cnt_news  = (int*)alloc(N_NEWS * 4);
    int* arena_cnt = (int*)alloc(P_USR * 4);
    size_t zero_bytes = o;
    int* cnt_usr   = (int*)alloc((size_t)N_USERS * 4);
    int* start_usr = (int*)alloc((size_t)N_USERS * 4);
    int* ids_atr  = (int*)alloc((size_t)N_ATR * ACAP * 4);
    int* ids_news = (int*)alloc((size_t)N_NEWS * NCAP * 4);
    int* ids_usr  = (int*)alloc((size_t)P_USR * ACAPP * 4);
    unsigned long long* arena = (unsigned long long*)alloc((size_t)P_USR * ACAPP * 8);
    ushort* news_bf    = (ushort*)alloc((size_t)N_NEWS * 768 * 2);
    ushort* users_bf   = (ushort*)alloc((size_t)N_USERS * 128 * 2);
    ushort* agr_atr_b  = (ushort*)alloc((size_t)N_ATR * 768 * 2);
    ushort* h_atr_b    = (ushort*)alloc((size_t)N_ATR * 256 * 2);
    ushort* atr_feats_b= (ushort*)alloc((size_t)N_ATR * 128 * 2);
    ushort* agr_news_b = (ushort*)alloc((size_t)N_NEWS * 128 * 2);
    ushort* agr_usr_b  = (ushort*)alloc((size_t)N_USERS * 128 * 2);
    ushort* out_news_b = (ushort*)alloc((size_t)N_NEWS * 128 * 2);
    ushort* h_buf      = (ushort*)alloc((size_t)N_USERS * 256 * 2);
    ushort* w1at = (ushort*)alloc((size_t)256 * 768 * 2);
    ushort* w1bt = (ushort*)alloc((size_t)128 * 256 * 2);
    ushort* wnat = (ushort*)alloc((size_t)512 * 896 * 2);
    ushort* wnbt = (ushort*)alloc((size_t)128 * 512 * 2);
    ushort* wuat = (ushort*)alloc((size_t)256 * 256 * 2);
    ushort* wubt = (ushort*)alloc((size_t)128 * 256 * 2);

    float* out = (float*)d_out;
    float* out_users = out + (size_t)N_NEWS * 128;

    hipMemsetAsync(cnt_atr, 0, zero_bytes, stream);

    // ---- fused prep ----
    {
        PrepArgs A;
        A.atr_row = atr_row; A.atr_col = atr_col;
        A.usr_row = usr_row; A.usr_col = usr_col;
        A.cnt_atr = cnt_atr; A.cnt_news = cnt_news; A.arena_cnt = arena_cnt;
        A.ids_atr = ids_atr; A.ids_news = ids_news;
        A.arena = arena;
        A.news_x = news_x; A.users_x = users_x;
        A.news_bf = news_bf; A.users_bf = users_bf;
        A.pa = (E_USR + EBLK_A - 1) / EBLK_A;     // 489
        A.fa = 25;
        A.n1 = N_NEWS * 768 / 4 / 512;            // 18750 tiles
        A.n2 = N_USERS * 128 / 4 / 512;           // 6250 tiles
        int acc2 = 0;
        auto add = [&](int i, const float* s, ushort* d, int R, int C) {
            acc2 += (C / 32) * (R / 32);
            A.j[i] = TrJob{s, d, R, C, acc2};
        };
        add(0, w1a, w1at, 768, 256);
        add(1, w1b, w1bt, 256, 128);
        add(2, wna, wnat, 896, 512);
        add(3, wnb, wnbt, 512, 128);
        add(4, wua, wuat, 256, 256);
        add(5, wub, wubt, 256, 128);
        A.tr = acc2;
        prep_k<<<A.pa + A.fa + A.tr + A.n1 + A.n2, 256, 0, stream>>>(A);
    }

    // ---- mid: usr pass B (CSR) + gather768 ----
    {
        MidArgs M;
        M.arena = arena; M.arena_cnt = arena_cnt;
        M.cnt_usr = cnt_usr; M.start_usr = start_usr; M.ids_usr = ids_usr;
        M.news_bf = news_bf; M.ids_atr = ids_atr; M.cnt_atr = cnt_atr;
        M.agr_atr_b = agr_atr_b;
        mid_k<<<P_USR + N_ATR, 256, 0, stream>>>(M);
    }

    // attr MLP
    gemm5_k<12, 12, true, 0, 2><<<16, 256, 0, stream>>>(
        agr_atr_b, nullptr, w1at, b1a, nullptr, h_atr_b, N_ATR, 256);
    gemm5_k<4, 4, false, 0, 1><<<8, 256, 0, stream>>>(
        h_atr_b, nullptr, w1bt, b1b, nullptr, atr_feats_b, N_ATR, 128);
    gather128c_k<NCAP><<<(N_NEWS + 7) / 8, 256, 0, stream>>>(
        atr_feats_b, ids_news, cnt_news, agr_news_b, N_NEWS);

    // news MLP
    gemm5_k<14, 12, true, 0, 4><<<391 * 4, 256, 0, stream>>>(
        news_bf, agr_news_b, wnat, bna, nullptr, h_buf, N_NEWS, 512);
    gemm5_k<8, 8, false, 2, 1><<<391, 256, 0, stream>>>(
        h_buf, nullptr, wnbt, bnb, out, out_news_b, N_NEWS, 128);

    // users pipeline
    gather128s_k<<<(N_USERS + 7) / 8, 256, 0, stream>>>(
        out_news_b, ids_usr, start_usr, cnt_usr, agr_usr_b, N_USERS);
    gemm5_k<4, 2, true, 0, 2><<<782 * 2, 256, 0, stream>>>(
        users_bf, agr_usr_b, wuat, bua, nullptr, h_buf, N_USERS, 256);
    gemm5_k<4, 4, false, 1, 1><<<782, 256, 0, stream>>>(
        h_buf, nullptr, wubt, bub, out_users, nullptr, N_USERS, 128);
}